// Round 1
// baseline (111.955 us; speedup 1.0000x reference)
//
#include <hip/hip_runtime.h>

#define MARGIN 0.2472f
#define SENT_NUM 16384
#define ANN_NUM 8192

// One block per row: load pos = att[row, pann[row]], then hinge-sum the whole
// row with float4 coalesced loads. The j==pann term contributes exactly MARGIN
// (att[i,pann]-pos == 0 in fp), so we include it and subtract S*MARGIN at the end.
__global__ __launch_bounds__(256) void hinge_row_kernel(
        const float* __restrict__ att,
        const int* __restrict__ pann,
        float* __restrict__ partials) {
    const int row = blockIdx.x;
    const float* rp = att + (size_t)row * ANN_NUM;
    const float pos = rp[pann[row]];           // L1/L2 hit for most lanes
    const float th = MARGIN - pos;

    const int t = threadIdx.x;
    const float4* rp4 = (const float4*)rp;     // row base is 32KB-aligned
    float acc = 0.0f;
    // 8192 floats = 2048 float4; 256 threads -> 8 float4 each, stride 256 for coalescing
    #pragma unroll
    for (int k = 0; k < 8; ++k) {
        float4 v = rp4[t + k * 256];
        acc += fmaxf(v.x + th, 0.0f);
        acc += fmaxf(v.y + th, 0.0f);
        acc += fmaxf(v.z + th, 0.0f);
        acc += fmaxf(v.w + th, 0.0f);
    }

    // wave64 shuffle reduce
    #pragma unroll
    for (int off = 32; off > 0; off >>= 1)
        acc += __shfl_down(acc, off, 64);

    __shared__ float wsum[4];
    const int lane = t & 63;
    const int wid  = t >> 6;
    if (lane == 0) wsum[wid] = acc;
    __syncthreads();
    if (t == 0)
        partials[row] = wsum[0] + wsum[1] + wsum[2] + wsum[3];
}

__global__ __launch_bounds__(256) void reduce_final_kernel(
        const float* __restrict__ partials,
        float* __restrict__ out) {
    double acc = 0.0;
    for (int i = threadIdx.x; i < SENT_NUM; i += 256)
        acc += (double)partials[i];

    #pragma unroll
    for (int off = 32; off > 0; off >>= 1)
        acc += __shfl_down(acc, off, 64);

    __shared__ double wsum[4];
    const int lane = threadIdx.x & 63;
    const int wid  = threadIdx.x >> 6;
    if (lane == 0) wsum[wid] = acc;
    __syncthreads();
    if (threadIdx.x == 0) {
        double total = wsum[0] + wsum[1] + wsum[2] + wsum[3];
        total -= (double)SENT_NUM * (double)MARGIN;   // remove the j==pann terms
        out[0] = (float)(total / ((double)SENT_NUM * (double)ANN_NUM));
    }
}

extern "C" void kernel_launch(void* const* d_in, const int* in_sizes, int n_in,
                              void* d_out, int out_size, void* d_ws, size_t ws_size,
                              hipStream_t stream) {
    const float* att  = (const float*)d_in[0];
    const int*   pann = (const int*)d_in[1];
    float* out      = (float*)d_out;
    float* partials = (float*)d_ws;   // SENT_NUM floats = 64 KiB

    hinge_row_kernel<<<SENT_NUM, 256, 0, stream>>>(att, pann, partials);
    reduce_final_kernel<<<1, 256, 0, stream>>>(partials, out);
}

// Round 2
// 96.471 us; speedup vs baseline: 1.1605x; 1.1605x over previous
//
#include <hip/hip_runtime.h>

#define MARGIN 0.2472f
#define SENT_NUM 16384
#define ANN_NUM 8192
#define RPB 8                      // rows per block
#define NBLK (SENT_NUM / RPB)      // 2048 blocks

// Each block handles 8 consecutive rows (256 KiB contiguous). pos thresholds
// for the 8 rows are gathered once into LDS, then the block streams the rows
// with float4 coalesced loads. The j==pann term contributes exactly MARGIN,
// so we sum over all j and subtract SENT_NUM*MARGIN at the end.
__global__ __launch_bounds__(256) void hinge_rows_kernel(
        const float* __restrict__ att,
        const int* __restrict__ pann,
        float* __restrict__ partials) {
    const int b = blockIdx.x;
    const int t = threadIdx.x;
    const int row0 = b * RPB;

    __shared__ float s_th[RPB];
    if (t < RPB)
        s_th[t] = MARGIN - att[(size_t)(row0 + t) * ANN_NUM + pann[row0 + t]];
    __syncthreads();

    const float4* base4 = (const float4*)(att + (size_t)row0 * ANN_NUM);
    float acc = 0.0f;
    // 8 rows x 2048 float4; 256 threads -> 8 float4/thread/row, stride 256
    #pragma unroll 2
    for (int r = 0; r < RPB; ++r) {
        const float4* rp4 = base4 + (size_t)r * (ANN_NUM / 4);
        const float th = s_th[r];
        #pragma unroll
        for (int k = 0; k < 8; ++k) {
            float4 v = rp4[t + k * 256];
            acc += fmaxf(v.x + th, 0.0f);
            acc += fmaxf(v.y + th, 0.0f);
            acc += fmaxf(v.z + th, 0.0f);
            acc += fmaxf(v.w + th, 0.0f);
        }
    }

    // wave64 shuffle reduce
    #pragma unroll
    for (int off = 32; off > 0; off >>= 1)
        acc += __shfl_down(acc, off, 64);

    __shared__ float wsum[4];
    if ((t & 63) == 0) wsum[t >> 6] = acc;
    __syncthreads();
    if (t == 0)
        partials[b] = wsum[0] + wsum[1] + wsum[2] + wsum[3];
}

__global__ __launch_bounds__(256) void reduce_final_kernel(
        const float* __restrict__ partials,
        float* __restrict__ out) {
    double acc = 0.0;
    #pragma unroll
    for (int i = 0; i < NBLK / 256; ++i)
        acc += (double)partials[threadIdx.x + i * 256];

    #pragma unroll
    for (int off = 32; off > 0; off >>= 1)
        acc += __shfl_down(acc, off, 64);

    __shared__ double wsum[4];
    if ((threadIdx.x & 63) == 0) wsum[threadIdx.x >> 6] = acc;
    __syncthreads();
    if (threadIdx.x == 0) {
        double total = wsum[0] + wsum[1] + wsum[2] + wsum[3];
        total -= (double)SENT_NUM * (double)MARGIN;   // remove the j==pann terms
        out[0] = (float)(total / ((double)SENT_NUM * (double)ANN_NUM));
    }
}

extern "C" void kernel_launch(void* const* d_in, const int* in_sizes, int n_in,
                              void* d_out, int out_size, void* d_ws, size_t ws_size,
                              hipStream_t stream) {
    const float* att  = (const float*)d_in[0];
    const int*   pann = (const int*)d_in[1];
    float* out      = (float*)d_out;
    float* partials = (float*)d_ws;   // NBLK floats = 8 KiB

    hinge_rows_kernel<<<NBLK, 256, 0, stream>>>(att, pann, partials);
    reduce_final_kernel<<<1, 256, 0, stream>>>(partials, out);
}